// Round 9
// baseline (107.401 us; speedup 1.0000x reference)
//
#include <hip/hip_runtime.h>

// Problem constants
constexpr int Bb = 1024;   // batch
constexpr int Ii = 256;    // in features
constexpr int Oo = 256;    // out features
constexpr int Kk = 128;    // knots
constexpr int NCH = 8;     // i-chunks (XCD-aligned)

typedef unsigned short u16;
typedef unsigned int u32;
typedef u16 ushort8v __attribute__((ext_vector_type(8)));
typedef float f4v __attribute__((ext_vector_type(4)));

__device__ __forceinline__ float bf16u_to_f(u16 u) {
    union { u32 ui; float f; } c;
    c.ui = ((u32)u) << 16;
    return c.f;
}
__device__ __forceinline__ u16 f_to_bf16(float f) {  // round-to-nearest-even
    union { float f; u32 u; } c; c.f = f;
    u32 r = c.u + 0x7fffu + ((c.u >> 16) & 1u);
    return (u16)(r >> 16);
}

// v_dot2_f32_bf16: acc += a.lo*b.lo + a.hi*b.hi with bf16 inputs.
// TARGET_BUILTIN => __has_builtin is false if gfx950 lacks the feature,
// in which case we fall back to the (verified) cvt+fmaf path.
#if __has_builtin(__builtin_amdgcn_fdot2_f32_bf16)
#define HAS_DOT2 1
typedef __bf16 bf2 __attribute__((ext_vector_type(2)));
__device__ __forceinline__ float fdot2bf(u32 ab, u32 cd, float acc) {
    union { u32 u; bf2 v; } A, B; A.u = ab; B.u = cd;
    return __builtin_amdgcn_fdot2_f32_bf16(A.v, B.v, acc, false);
}
#endif

// Kernel A: permute+scale Cs[o][i][k] -> Cp[i][k][o] bf16 via LDS transpose.
// XCD-aligned numbering (chunk = blk & 7): chunk c's 2 MB Cp slice is written
// by XCD c and stays cache-resident for kmain's gathers (R4: kmain FETCH
// 8.9 MB vs 256 MB gather volume -> locality verified).
// cs reads non-temporal (32 MB read-once stream must not evict cp).
// Tail: blocks <256 transpose wbase -> wt (bf16).
// NO fences, NO atomics (R3: in-kernel device fences = L2 flush storm;
// R4: cross-XCD shared-line atomics = HBM-side RMW storm). Kernel boundary
// is the coherence point.
__global__ __launch_bounds__(256) void kperm(const float* __restrict__ cs,
                                             const float* __restrict__ scale,
                                             const float* __restrict__ wbase,
                                             u16* __restrict__ cp,
                                             u16* __restrict__ wt) {
    __shared__ u16 T[128 * 66];       // [o_local][k_local], pitch 66
    int blk = blockIdx.x;
    int chunk = blk & 7;
    int sub = blk >> 3;               // 0..127
    int i  = chunk * 32 + (sub & 31); // i within this XCD's chunk
    int oh = (sub >> 5) & 1, kh = (sub >> 6) & 1;
    int o0 = oh << 7, kb = kh << 6;
    int t = threadIdx.x;

    // Phase 1: load Cs rows (float4 along k, nt), scale, bf16 -> LDS
    {
        int c4 = t & 15;              // float4 index within the 64-k half
        int rb = t >> 4;              // 0..15
        const f4v* cs4 = (const f4v*)cs;
#pragma unroll
        for (int p = 0; p < 8; ++p) {
            int r = p * 16 + rb;      // o_local 0..127
            int o = o0 + r;
            float sc = scale[o * Ii + i];
            f4v val = __builtin_nontemporal_load(
                &cs4[(size_t)(o * Ii + i) * (Kk / 4) + kh * 16 + c4]);
            int kl = c4 * 4;
            T[r * 66 + kl + 0] = f_to_bf16(val.x * sc);
            T[r * 66 + kl + 1] = f_to_bf16(val.y * sc);
            T[r * 66 + kl + 2] = f_to_bf16(val.z * sc);
            T[r * 66 + kl + 3] = f_to_bf16(val.w * sc);
        }
    }
    __syncthreads();
    // Phase 2: write Cp[i][kb+kl][o0..o0+128], lanes <-> o (u32 = 2 o).
    {
        int og = t & 63;              // o-pair index
        int kg = t >> 6;              // 0..3, 16 k-rows each
#pragma unroll
        for (int m = 0; m < 16; ++m) {
            int kl = kg * 16 + m;
            u32 lo = T[(og * 2) * 66 + kl];
            u32 hi = T[(og * 2 + 1) * 66 + kl];
            *(u32*)&cp[((size_t)i * Kk + kb + kl) * Oo + o0 + og * 2] = lo | (hi << 16);
        }
    }
    // Tail: Wt[i][o] = bf16(W[o][i]) (65536 elems across blocks 0..255)
    if (blk < 256) {
        int gid = blk * 256 + t;
        wt[gid] = f_to_bf16(
            __builtin_nontemporal_load(&wbase[(gid & 255) * Ii + (gid >> 8)]));
    }
}

// Kernel B: main accumulation. 1024 blocks = 128 b-tiles x 8 i-chunks.
// 8 blocks/CU (LDS 20 KB = sf 4 KB + wbuf 16 KB), 32 waves/CU.
// Thread = 1 b x 8 o; 2 x 16 B ushort8 gathers per i-iter from the
// XCD-local cp slice (R4: cache-hit verified).
// R9: inner loop uses v_dot2_f32_bf16 when available — packed (g,f)x(cl,cr)
// and (s,0)x(w0,w1) dot2s replace 24 cvt + 24 fmaf with ~8 perm + 16 dot2
// (zero converts). Partials stored as bf16 (halves part roundtrip).
__global__ __launch_bounds__(256, 8) void kmain(const float* __restrict__ x,
                                                const char* __restrict__ cpb,
                                                const u16* __restrict__ wt,
                                                u16* __restrict__ part) {
    __shared__ float4 sf[256];           // [bl][il] : 8 b x 32 i    (4 KB)
    __shared__ u16 wbuf[32 * 256];       // [m][o] bf16 w rows      (16 KB)
    int t = threadIdx.x;
    int blk = blockIdx.x;
    int chunk = blk & (NCH - 1);
    int b0 = (blk >> 3) << 3;            // b-tile * 8
    int i0 = chunk << 5;                 // 32 i per chunk

    {                                    // prep: 1 (b,i) value per thread
        int il = t & 31, bl = t >> 5;    // coalesced x reads along il
        float xv = __builtin_nontemporal_load(
            &x[(size_t)(b0 + bl) * Ii + i0 + il]);
        float e2 = __expf(2.f * xv);
        float p = 1.f - 2.f / (e2 + 1.f);   // tanh
        float s = p / (1.f + __expf(-p));   // silu(p)
        float c = fminf(fmaxf(p, -1.f), 1.f);
        float scaled = (c + 1.f) * ((float)(Kk - 1) * 0.5f);
        int l = (int)floorf(scaled);
        l = min(max(l, 0), Kk - 1);
        int rr = min(l + 1, Kk - 1);
        float frac = scaled - (float)l;
        float4 v;
        // packed bf16 weights: (g | f<<16) and (s | 0<<16)
        v.x = __uint_as_float((u32)f_to_bf16(1.f - frac) |
                              ((u32)f_to_bf16(frac) << 16));
        v.y = __uint_as_float((u32)f_to_bf16(s));
        v.z = __int_as_float(l * (Oo * 2));  // byte ofs, left row in [k][o] slab
        v.w = __int_as_float(rr * (Oo * 2)); // byte ofs, right row
        sf[bl * 32 + il] = v;                // 16 B/lane stride: conflict-free
    }
    {                                    // stage 32 bf16 w-rows (16 KB)
        const ushort8v* wsrc = (const ushort8v*)(wt + (size_t)i0 * Oo);
        ushort8v* wdst = (ushort8v*)wbuf;
#pragma unroll
        for (int p = 0; p < 4; ++p)      // 1024 x 16 B chunks, coalesced
            wdst[t + p * 256] = wsrc[t + p * 256];
    }
    __syncthreads();                     // wbuf is cross-wave shared

    int oq = t & 31;                     // o = oq*8 .. oq*8+7
    int bl = t >> 5;                     // b = b0 + bl
    float a[8] = {0.f,0.f,0.f,0.f,0.f,0.f,0.f,0.f};
    const char* cbase = cpb + (size_t)i0 * (Kk * Oo * 2) + oq * 16;

#pragma unroll 2
    for (int m = 0; m < 32; ++m) {
        float4 v = sf[bl * 32 + m];                  // broadcast (2 addrs/wave)
        uint4 wq = *(const uint4*)&wbuf[m * 256 + oq * 8];   // 4x(w_j|w_j+1)
        const char* ci = cbase + (size_t)m * (Kk * Oo * 2);
        uint4 clq = *(const uint4*)(ci + __float_as_int(v.z));  // 16 B gather
        uint4 crq = *(const uint4*)(ci + __float_as_int(v.w));  // 16 B gather
#ifdef HAS_DOT2
        u32 gf = __float_as_uint(v.x);               // (g | f<<16)
        u32 se = __float_as_uint(v.y);               // (s | 0)
        u32 so = se << 16;                           // (0 | s)
        u32 cl32[4] = {clq.x, clq.y, clq.z, clq.w};
        u32 cr32[4] = {crq.x, crq.y, crq.z, crq.w};
        u32 wv32[4] = {wq.x, wq.y, wq.z, wq.w};
#pragma unroll
        for (int jp = 0; jp < 4; ++jp) {
            // pair (cl_j, cr_j) / (cl_j+1, cr_j+1) via byte-perm
            u32 pe = __builtin_amdgcn_perm(cr32[jp], cl32[jp], 0x05040100u);
            u32 po = __builtin_amdgcn_perm(cr32[jp], cl32[jp], 0x07060302u);
            a[2*jp]   = fdot2bf(gf, pe, a[2*jp]);    // g*cl + f*cr
            a[2*jp+1] = fdot2bf(gf, po, a[2*jp+1]);
            a[2*jp]   = fdot2bf(se, wv32[jp], a[2*jp]);    // s*w_even
            a[2*jp+1] = fdot2bf(so, wv32[jp], a[2*jp+1]);  // s*w_odd
        }
#else
        // fallback: unpack bf16 + scalar fmaf (R8-verified path)
        u32 gfu = __float_as_uint(v.x);
        float g = bf16u_to_f((u16)(gfu & 0xffffu));
        float f = bf16u_to_f((u16)(gfu >> 16));
        float s = bf16u_to_f((u16)(__float_as_uint(v.y) & 0xffffu));
        const ushort8v cl = *(const ushort8v*)&clq;
        const ushort8v cr = *(const ushort8v*)&crq;
        const ushort8v wv = *(const ushort8v*)&wq;
#pragma unroll
        for (int j = 0; j < 8; ++j) {
            a[j] = fmaf(s, bf16u_to_f(wv[j]), a[j]);
            a[j] = fmaf(g, bf16u_to_f(cl[j]), a[j]);
            a[j] = fmaf(f, bf16u_to_f(cr[j]), a[j]);
        }
#endif
    }

    // pack accumulators to bf16 pairs, one 16 B store
    uint4 pk;
    pk.x = (u32)f_to_bf16(a[0]) | ((u32)f_to_bf16(a[1]) << 16);
    pk.y = (u32)f_to_bf16(a[2]) | ((u32)f_to_bf16(a[3]) << 16);
    pk.z = (u32)f_to_bf16(a[4]) | ((u32)f_to_bf16(a[5]) << 16);
    pk.w = (u32)f_to_bf16(a[6]) | ((u32)f_to_bf16(a[7]) << 16);
    *(uint4*)&part[(size_t)chunk * (Bb * Oo) + (size_t)(b0 + bl) * Oo + oq * 8] = pk;
}

// Kernel C: out[b][o] = bias[o] + sum_c partial[c][b][o]. 256 blocks.
// part is bf16 (u16); thread handles 4 o's (2 u32 per chunk), nt reads.
__global__ __launch_bounds__(256) void kreduce(const u32* __restrict__ part2,
                                               const float4* __restrict__ bias4,
                                               float4* __restrict__ out4) {
    int gid = blockIdx.x * 256 + threadIdx.x;     // = b*64 + o4
    const u32* p = part2 + (size_t)gid * 2;
    float s0 = 0.f, s1 = 0.f, s2 = 0.f, s3 = 0.f;
#pragma unroll
    for (int c = 0; c < NCH; ++c) {
        u32 lo = __builtin_nontemporal_load(p + (size_t)c * (Bb * Oo / 2));
        u32 hi = __builtin_nontemporal_load(p + (size_t)c * (Bb * Oo / 2) + 1);
        s0 += bf16u_to_f((u16)(lo & 0xffffu));
        s1 += bf16u_to_f((u16)(lo >> 16));
        s2 += bf16u_to_f((u16)(hi & 0xffffu));
        s3 += bf16u_to_f((u16)(hi >> 16));
    }
    float4 bv = bias4[gid & 63];
    float4 o;
    o.x = s0 + bv.x; o.y = s1 + bv.y; o.z = s2 + bv.z; o.w = s3 + bv.w;
    out4[gid] = o;
}

extern "C" void kernel_launch(void* const* d_in, const int* in_sizes, int n_in,
                              void* d_out, int out_size, void* d_ws, size_t ws_size,
                              hipStream_t stream) {
    const float* x     = (const float*)d_in[0];
    const float* wbase = (const float*)d_in[1];
    const float* coeff = (const float*)d_in[2];
    const float* scale = (const float*)d_in[3];
    const float* bias  = (const float*)d_in[4];
    float* out = (float*)d_out;

    char* ws = (char*)d_ws;
    u16* cp   = (u16*)ws;                             // 16 MB  @ 0
    u16* wt   = (u16*)(ws + (16u << 20));             // 128 KB @ 16M
    u16* part = (u16*)(ws + (17u << 20));             // 4 MB   @ 17M

    kperm<<<1024, 256, 0, stream>>>(coeff, scale, wbase, cp, wt);
    kmain<<<1024, 256, 0, stream>>>(x, (const char*)cp, wt, part);
    kreduce<<<(Bb * Oo / 4) / 256, 256, 0, stream>>>((const u32*)part,
                                                     (const float4*)bias,
                                                     (float4*)out);
}